// Round 5
// baseline (442.295 us; speedup 1.0000x reference)
//
#include <hip/hip_runtime.h>
#include <stddef.h>

// ---------------------------------------------------------------------------
// 2-layer GCN, bf16 intermediates + MFMA GEMMs + bucketed CSR build.
// h = relu(Agg(x@W1)+b1); h = relu(Agg(h@W2)+b2); out = mean pool per graph.
// GEMM v2: persistent blocks, B(hi+lo) in registers, A double-buffered LDS.
// Agg v2: 2 waves per node (edge-split) for 2x outstanding gathers.
// ---------------------------------------------------------------------------

#define F 128
#define EB 4096          // edges per passB block
#define BSH 9            // bucket = dst >> 9 (512 nodes per bucket)

typedef unsigned int uint;
typedef unsigned short ushort;
typedef __attribute__((ext_vector_type(8))) short s16x8;   // 8 bf16
typedef __attribute__((ext_vector_type(4))) float f32x4;

__device__ __forceinline__ float bf_lo(uint v) { return __uint_as_float(v << 16); }
__device__ __forceinline__ float bf_hi(uint v) { return __uint_as_float(v & 0xffff0000u); }
__device__ __forceinline__ ushort f2bf(float f) {
    uint u = __float_as_uint(f);
    u += 0x7fffu + ((u >> 16) & 1u);   // RNE
    return (ushort)(u >> 16);
}
__device__ __forceinline__ uint pack_bf2(float lo, float hi) {
    return (uint)f2bf(lo) | ((uint)f2bf(hi) << 16);
}

// inclusive Hillis-Steele scan over 256 entries (all 256 threads must call)
__device__ __forceinline__ int scan256_incl(int* s, int t, int v) {
    s[t] = v;
    __syncthreads();
#pragma unroll
    for (int d = 1; d < 256; d <<= 1) {
        int y = (t >= d) ? s[t - d] : 0;
        __syncthreads();
        s[t] += y;
        __syncthreads();
    }
    return s[t];
}

// ---------------- pass A: coarse bucket histogram --------------------------

__global__ __launch_bounds__(256) void passA_kernel(const int* __restrict__ ei,
                                                    int* __restrict__ bucket_cnt,
                                                    int e, int nbuc) {
    __shared__ int h[256];
    int t = threadIdx.x;
    h[t] = 0;
    __syncthreads();
    for (int i = blockIdx.x * 256 + t; i < e; i += gridDim.x * 256)
        atomicAdd(&h[ei[e + i] >> BSH], 1);
    __syncthreads();
    if (t < nbuc && h[t]) atomicAdd(&bucket_cnt[t], h[t]);
}

// ---------------- W prep (blocks 0..127) + bucket scan (block 128) ---------

__global__ __launch_bounds__(256) void prep_scan_kernel(const float* __restrict__ W1,
                                                        const float* __restrict__ W2,
                                                        ushort* __restrict__ wt,
                                                        const int* __restrict__ bucket_cnt,
                                                        int* __restrict__ bucket_base,
                                                        int* __restrict__ gcur, int nbuc) {
    if (blockIdx.x == 128) {
        __shared__ int aux[256];
        int t = threadIdx.x;
        int v = (t < nbuc) ? bucket_cnt[t] : 0;
        int incl = scan256_incl(aux, t, v);
        int base = incl - v;
        bucket_base[t] = base;
        gcur[t] = base;
        if (t == nbuc - 1) bucket_base[nbuc] = incl;
        return;
    }
    int idx = blockIdx.x * 256 + threadIdx.x;     // 2*128*128 elements
    int m = idx >> 14;
    int c = (idx >> 7) & 127;
    int r = idx & 127;
    const float* W = m ? W2 : W1;
    float w = W[r * F + c];
    ushort hi = f2bf(w);
    float whi = __uint_as_float((uint)hi << 16);
    ushort lo = f2bf(w - whi);
    wt[((m * 2 + 0) * F + c) * F + r] = hi;
    wt[((m * 2 + 1) * F + c) * F + r] = lo;
}

// ---------------- pass B: bucketed edge dump (LDS multisplit) --------------

__global__ __launch_bounds__(256) void passB_kernel(const int* __restrict__ ei,
                                                    int* __restrict__ gcur,
                                                    uint2* __restrict__ ebuf, int e) {
    __shared__ uint2 stage[EB];
    __shared__ int h[256], start[256], cur[256], claim[256], aux[256];
    int t = threadIdx.x;
    h[t] = 0;
    __syncthreads();
    int base = blockIdx.x * EB;
    int s_r[16], d_r[16];
#pragma unroll
    for (int k = 0; k < 16; ++k) {
        int i = base + k * 256 + t;
        int sv = -1, dv = 0;
        if (i < e) {
            sv = ei[i];
            dv = ei[e + i];
            atomicAdd(&h[dv >> BSH], 1);
        }
        s_r[k] = sv; d_r[k] = dv;
    }
    __syncthreads();
    int hv = h[t];
    int incl = scan256_incl(aux, t, hv);
    start[t] = incl - hv;
    cur[t]   = incl - hv;
    claim[t] = (hv > 0) ? atomicAdd(&gcur[t], hv) : 0;
    __syncthreads();
#pragma unroll
    for (int k = 0; k < 16; ++k) {
        if (s_r[k] >= 0) {
            int b = d_r[k] >> BSH;
            int r = atomicAdd(&cur[b], 1);
            stage[r] = make_uint2((uint)s_r[k], (uint)d_r[k]);
        }
    }
    __syncthreads();
    int valid = min(EB, e - base);
#pragma unroll
    for (int k = 0; k < 16; ++k) {
        int idx = k * 256 + t;
        if (idx < valid) {
            uint2 ed = stage[idx];
            int b = (int)(ed.y >> BSH);
            ebuf[claim[b] + (idx - start[b])] = ed;
        }
    }
}

// ---------------- pass C1: per-bucket fine hist -> rp, dis -----------------

__global__ __launch_bounds__(256) void passC1_kernel(const uint2* __restrict__ ebuf,
                                                     const int* __restrict__ bucket_base,
                                                     int* __restrict__ rp,
                                                     float* __restrict__ dis, int n) {
    __shared__ int h[512];
    __shared__ int aux[256];
    int t = threadIdx.x, b = blockIdx.x;
    int v0 = b << BSH;
    h[t] = 0; h[t + 256] = 0;
    __syncthreads();
    int ebeg = bucket_base[b], eend = bucket_base[b + 1];
    for (int i = ebeg + t; i < eend; i += 256)
        atomicAdd(&h[(int)ebuf[i].y - v0], 1);
    __syncthreads();
#pragma unroll
    for (int k = 0; k < 2; ++k) {
        int v = v0 + t + k * 256;
        if (v < n) dis[v] = rsqrtf((float)(h[t + k * 256] + 1));
    }
    int p = h[2 * t] + h[2 * t + 1];
    int incl = scan256_incl(aux, t, p);
    int ex = incl - p;
    int v = v0 + 2 * t;
    if (v <= n)     rp[v]     = ebeg + ex;
    if (v + 1 <= n) rp[v + 1] = ebeg + ex + h[2 * t];
}

// ---------------- pass C2: per-bucket scatter -> ew=(src, norm) ------------

__global__ __launch_bounds__(256) void passC2_kernel(const uint2* __restrict__ ebuf,
                                                     const int* __restrict__ bucket_base,
                                                     const int* __restrict__ rp,
                                                     const float* __restrict__ dis,
                                                     uint2* __restrict__ ew, int n) {
    __shared__ int cur[512];
    __shared__ float dl[512];
    int t = threadIdx.x, b = blockIdx.x;
    int v0 = b << BSH;
#pragma unroll
    for (int k = 0; k < 2; ++k) {
        int idx = t + k * 256, v = v0 + idx;
        cur[idx] = (v < n) ? rp[v] : 0;
        dl[idx]  = (v < n) ? dis[v] : 0.f;
    }
    __syncthreads();
    int ebeg = bucket_base[b], eend = bucket_base[b + 1];
    for (int i = ebeg + t; i < eend; i += 256) {
        uint2 ed = ebuf[i];
        int s = (int)ed.x, d = (int)ed.y - v0;
        float w = dis[s] * dl[d];
        int p = atomicAdd(&cur[d], 1);
        ew[p] = make_uint2(ed.x, __float_as_uint(w));
    }
}

// ---------------- GEMM v2: persistent, B-in-registers ----------------------
// grid ~261 blocks x 256 thr = 4 waves; wave w owns cols [w*32, w*32+32).
// Per strip (128 rows): A staged bf16 swizzled LDS (double-buffered),
// 128 MFMA/wave, C via LDS-reuse epilogue. B (hi+lo) loaded once to VGPRs.

template <bool F32IN>
__global__ __launch_bounds__(256) void gemm_mfma_kernel(const float* __restrict__ Af,
                                                        const uint* __restrict__ Ab,
                                                        const ushort* __restrict__ wt,
                                                        ushort* __restrict__ C,
                                                        int n, int nstrips) {
    __shared__ uint4 As4[2][2048];       // 2 x 32 KB
    const int t = threadIdx.x;
    const int w = t >> 6;
    const int lane = t & 63;
    const int kg = lane >> 4;            // k-group 0..3
    const int lr = lane & 15;

    // ---- B fragments, whole kernel ----
    const uint4* Bg = (const uint4*)wt;  // [part][col][kgran] 16B granules
    s16x8 bfr[2][2][4];                  // [part][ctile][ks]
#pragma unroll
    for (int part = 0; part < 2; ++part)
#pragma unroll
        for (int c = 0; c < 2; ++c)
#pragma unroll
            for (int ks = 0; ks < 4; ++ks) {
                int col = w * 32 + c * 16 + lr;
                uint4 bu = Bg[part * F * 16 + col * 16 + ks * 4 + kg];
                bfr[part][c][ks] = *(const s16x8*)&bu;
            }

    auto load_strip = [&](int strip, uint4* st) {
        int r0 = strip * 128;
#pragma unroll
        for (int p = 0; p < 8; ++p) {
            int g = p * 256 + t;
            int row = g >> 4, q = g & 15;
            int c8 = q ^ (row & 7);          // pre-swizzled source granule
            uint4 v = make_uint4(0u, 0u, 0u, 0u);
            int gr = r0 + row;
            if (gr < n) {
                if (F32IN) {
                    const float* a = Af + (size_t)gr * F + c8 * 8;
                    float4 f0 = *(const float4*)a;
                    float4 f1 = *(const float4*)(a + 4);
                    v.x = pack_bf2(f0.x, f0.y);
                    v.y = pack_bf2(f0.z, f0.w);
                    v.z = pack_bf2(f1.x, f1.y);
                    v.w = pack_bf2(f1.z, f1.w);
                } else {
                    v = *(const uint4*)(Ab + (size_t)gr * 64 + c8 * 4);
                }
            }
            st[p] = v;
        }
    };

    int s = blockIdx.x;
    if (s >= nstrips) return;
    uint4 st[8];
    load_strip(s, st);
    int buf = 0;
    for (; s < nstrips; s += gridDim.x) {
#pragma unroll
        for (int p = 0; p < 8; ++p) As4[buf][p * 256 + t] = st[p];
        __syncthreads();
        int s2 = s + gridDim.x;
        if (s2 < nstrips) load_strip(s2, st);   // overlaps with compute

        f32x4 acc[8][2];
#pragma unroll
        for (int r = 0; r < 8; ++r)
#pragma unroll
            for (int c = 0; c < 2; ++c) acc[r][c] = (f32x4){0.f, 0.f, 0.f, 0.f};

        const s16x8* As8 = (const s16x8*)As4[buf];
#pragma unroll
        for (int ks = 0; ks < 4; ++ks) {
            s16x8 afr[8];
#pragma unroll
            for (int r = 0; r < 8; ++r) {
                int row = r * 16 + lr;
                afr[r] = As8[row * 16 + ((ks * 4 + kg) ^ (row & 7))];
            }
#pragma unroll
            for (int r = 0; r < 8; ++r)
#pragma unroll
                for (int c = 0; c < 2; ++c) {
                    acc[r][c] = __builtin_amdgcn_mfma_f32_16x16x32_bf16(afr[r], bfr[0][c][ks], acc[r][c], 0, 0, 0);
                    acc[r][c] = __builtin_amdgcn_mfma_f32_16x16x32_bf16(afr[r], bfr[1][c][ks], acc[r][c], 0, 0, 0);
                }
        }
        __syncthreads();

        // epilogue: bf16 C into the just-consumed buffer, then coalesced out
        ushort* Cs = (ushort*)As4[buf];
#pragma unroll
        for (int r = 0; r < 8; ++r)
#pragma unroll
            for (int c = 0; c < 2; ++c)
#pragma unroll
                for (int reg = 0; reg < 4; ++reg) {
                    int row = r * 16 + kg * 4 + reg;
                    int col = w * 32 + c * 16 + lr;
                    Cs[row * F + col] = f2bf(acc[r][c][reg]);
                }
        __syncthreads();
        int r0 = s * 128;
#pragma unroll
        for (int p = 0; p < 8; ++p) {
            int g = p * 256 + t;
            int row = g >> 4, c8 = g & 15;
            if (r0 + row < n)
                *(uint4*)(C + (size_t)(r0 + row) * F + c8 * 8) = As4[buf][g];
        }
        buf ^= 1;
    }
}

// ---------------- pull aggregation v2: 2 waves per node --------------------
// block = 256 thr = 4 waves = 2 nodes; waves (sub=0/1) split edges even/odd;
// partials combined via LDS; lane owns cols {2*lane, 2*lane+1}.

__global__ __launch_bounds__(256) void agg_kernel(const uint* __restrict__ h2,
                                                  const int* __restrict__ rp,
                                                  const uint2* __restrict__ ew,
                                                  const float* __restrict__ dis,
                                                  const float* __restrict__ bias,
                                                  uint* __restrict__ out2, int n) {
    __shared__ float redx[2][64], redy[2][64];
    int t = threadIdx.x;
    int w = t >> 6;
    int lane = t & 63;
    int pair = w >> 1;
    int sub = w & 1;
    int node = blockIdx.x * 2 + pair;
    bool active = node < n;
    float ax = 0.f, ay = 0.f;
    int beg = 0, end = 0;
    if (active) { beg = rp[node]; end = rp[node + 1]; }
    int j = beg + sub;
    for (; j + 6 < end; j += 8) {
        uint2 E0 = ew[j], E1 = ew[j + 2], E2 = ew[j + 4], E3 = ew[j + 6];
        uint v0 = h2[(E0.x << 6) | lane];
        uint v1 = h2[(E1.x << 6) | lane];
        uint v2 = h2[(E2.x << 6) | lane];
        uint v3 = h2[(E3.x << 6) | lane];
        float w0e = __uint_as_float(E0.y), w1e = __uint_as_float(E1.y);
        float w2e = __uint_as_float(E2.y), w3e = __uint_as_float(E3.y);
        ax = fmaf(w0e, bf_lo(v0), ax); ay = fmaf(w0e, bf_hi(v0), ay);
        ax = fmaf(w1e, bf_lo(v1), ax); ay = fmaf(w1e, bf_hi(v1), ay);
        ax = fmaf(w2e, bf_lo(v2), ax); ay = fmaf(w2e, bf_hi(v2), ay);
        ax = fmaf(w3e, bf_lo(v3), ax); ay = fmaf(w3e, bf_hi(v3), ay);
    }
    for (; j < end; j += 2) {
        uint2 E0 = ew[j];
        uint v0 = h2[(E0.x << 6) | lane];
        float w0e = __uint_as_float(E0.y);
        ax = fmaf(w0e, bf_lo(v0), ax);
        ay = fmaf(w0e, bf_hi(v0), ay);
    }
    if (sub == 1) { redx[pair][lane] = ax; redy[pair][lane] = ay; }
    __syncthreads();
    if (active && sub == 0) {
        float di = dis[node];
        float w0 = di * di;
        uint hv = h2[((uint)node << 6) | lane];
        ax += redx[pair][lane] + w0 * bf_lo(hv);
        ay += redy[pair][lane] + w0 * bf_hi(hv);
        float2 b = ((const float2*)bias)[lane];
        ax = fmaxf(ax + b.x, 0.f);
        ay = fmaxf(ay + b.y, 0.f);
        out2[((uint)node << 6) | lane] = pack_bf2(ax, ay);
    }
}

// ---------------- global mean pool (batch sorted, bf16 in, f32 out) --------

__global__ __launch_bounds__(256) void pool_kernel(const uint* __restrict__ h2,
                                                   const int* __restrict__ batch,
                                                   float* __restrict__ out, int n) {
    __shared__ int sb[2];
    __shared__ float red[4][F];
    int g = blockIdx.x;
    int t = threadIdx.x;
    if (t < 2) {
        int target = g + t;
        int lo = 0, hi = n;
        while (lo < hi) {
            int mid = (lo + hi) >> 1;
            if (batch[mid] < target) lo = mid + 1; else hi = mid;
        }
        sb[t] = lo;
    }
    __syncthreads();
    int start = sb[0], end = sb[1];
    int lane = t & 63, w = t >> 6;
    float sx = 0.f, sy = 0.f;
    for (int i = start + w; i < end; i += 4) {
        uint v = h2[((uint)i << 6) | lane];
        sx += bf_lo(v);
        sy += bf_hi(v);
    }
    red[w][lane * 2] = sx;
    red[w][lane * 2 + 1] = sy;
    __syncthreads();
    if (w == 0) {
        float s0 = red[0][lane * 2] + red[1][lane * 2] + red[2][lane * 2] + red[3][lane * 2];
        float s1 = red[0][lane * 2 + 1] + red[1][lane * 2 + 1] + red[2][lane * 2 + 1] + red[3][lane * 2 + 1];
        float inv = 1.f / fmaxf((float)(end - start), 1.f);
        out[(size_t)g * F + lane * 2]     = s0 * inv;
        out[(size_t)g * F + lane * 2 + 1] = s1 * inv;
    }
}

// ---------------------------------------------------------------------------

extern "C" void kernel_launch(void* const* d_in, const int* in_sizes, int n_in,
                              void* d_out, int out_size, void* d_ws, size_t ws_size,
                              hipStream_t stream) {
    const float* x     = (const float*)d_in[0];
    const int*   ei    = (const int*)d_in[1];
    const int*   batch = (const int*)d_in[2];
    const float* W1    = (const float*)d_in[3];
    const float* b1    = (const float*)d_in[4];
    const float* W2    = (const float*)d_in[5];
    const float* b2    = (const float*)d_in[6];
    float* out = (float*)d_out;

    const int n = in_sizes[0] / F;       // 100000
    const int e = in_sizes[1] / 2;       // 1600000
    const int g = out_size / F;          // 512
    const int nbuc = (n + (1 << BSH) - 1) >> BSH;   // 196

    char* ws = (char*)d_ws;
    size_t off = 0;
    auto alloc = [&](size_t bytes) -> char* {
        char* p = ws + off;
        off += (bytes + 255) & ~(size_t)255;
        return p;
    };
    float*  dis   = (float*)alloc((size_t)n * 4);
    int*    rp    = (int*)  alloc((size_t)(n + 1) * 4);
    int*    bcnt  = (int*)  alloc(256 * 4);
    int*    bbase = (int*)  alloc(257 * 4);
    int*    gcur  = (int*)  alloc(256 * 4);
    uint2*  ebuf  = (uint2*)alloc((size_t)e * 8);
    uint2*  ew    = (uint2*)alloc((size_t)e * 8);
    ushort* wt    = (ushort*)alloc((size_t)4 * F * F * 2);
    uint*   hbuf  = (uint*) alloc((size_t)n * F * 2);
    uint*   abuf  = (uint*) alloc((size_t)n * F * 2);
    (void)ws_size;

    // --- CSR build (bucketed) + W prep ---
    hipMemsetAsync(bcnt, 0, 256 * 4, stream);
    passA_kernel<<<256, 256, 0, stream>>>(ei, bcnt, e, nbuc);
    prep_scan_kernel<<<129, 256, 0, stream>>>(W1, W2, wt, bcnt, bbase, gcur, nbuc);
    passB_kernel<<<(e + EB - 1) / EB, 256, 0, stream>>>(ei, gcur, ebuf, e);
    passC1_kernel<<<nbuc, 256, 0, stream>>>(ebuf, bbase, rp, dis, n);
    passC2_kernel<<<nbuc, 256, 0, stream>>>(ebuf, bbase, rp, dis, ew, n);

    const int nstrips = (n + 127) / 128;
    const int ggrid = nstrips < 261 ? nstrips : 261;
    // --- layer 1 ---
    gemm_mfma_kernel<true><<<ggrid, 256, 0, stream>>>(x, nullptr, wt, (ushort*)hbuf, n, nstrips);
    agg_kernel<<<(n + 1) / 2, 256, 0, stream>>>(hbuf, rp, ew, dis, b1, abuf, n);
    // --- layer 2 ---
    gemm_mfma_kernel<false><<<ggrid, 256, 0, stream>>>(nullptr, abuf, wt + 2 * F * F, (ushort*)hbuf, n, nstrips);
    agg_kernel<<<(n + 1) / 2, 256, 0, stream>>>(hbuf, rp, ew, dis, b2, abuf, n);
    // --- pool ---
    pool_kernel<<<g, 256, 0, stream>>>(abuf, batch, out, n);
}

// Round 7
// 349.839 us; speedup vs baseline: 1.2643x; 1.2643x over previous
//
#include <hip/hip_runtime.h>
#include <stddef.h>

// ---------------------------------------------------------------------------
// 2-layer GCN, bf16 intermediates + MFMA GEMMs + bucketed CSR build.
// h = relu(Agg(x@W1)+b1); h = relu(Agg(h@W2)+b2); out = mean pool per graph.
// GEMM: persistent blocks (2/CU), B(hi+lo) in registers, A dbuf LDS.
// Agg: 1 wave per node, 16 outstanding gathers (latency-bound regime).
// ---------------------------------------------------------------------------

#define F 128
#define EB 4096          // edges per passB block
#define BSH 9            // bucket = dst >> 9 (512 nodes per bucket)

typedef unsigned int uint;
typedef unsigned short ushort;
typedef __attribute__((ext_vector_type(8))) short s16x8;   // 8 bf16
typedef __attribute__((ext_vector_type(4))) float f32x4;

__device__ __forceinline__ float bf_lo(uint v) { return __uint_as_float(v << 16); }
__device__ __forceinline__ float bf_hi(uint v) { return __uint_as_float(v & 0xffff0000u); }
__device__ __forceinline__ ushort f2bf(float f) {
    uint u = __float_as_uint(f);
    u += 0x7fffu + ((u >> 16) & 1u);   // RNE
    return (ushort)(u >> 16);
}
__device__ __forceinline__ uint pack_bf2(float lo, float hi) {
    return (uint)f2bf(lo) | ((uint)f2bf(hi) << 16);
}

// inclusive Hillis-Steele scan over 256 entries (all 256 threads must call)
__device__ __forceinline__ int scan256_incl(int* s, int t, int v) {
    s[t] = v;
    __syncthreads();
#pragma unroll
    for (int d = 1; d < 256; d <<= 1) {
        int y = (t >= d) ? s[t - d] : 0;
        __syncthreads();
        s[t] += y;
        __syncthreads();
    }
    return s[t];
}

// ---------------- pass A: coarse bucket histogram --------------------------

__global__ __launch_bounds__(256) void passA_kernel(const int* __restrict__ ei,
                                                    int* __restrict__ bucket_cnt,
                                                    int e, int nbuc) {
    __shared__ int h[256];
    int t = threadIdx.x;
    h[t] = 0;
    __syncthreads();
    for (int i = blockIdx.x * 256 + t; i < e; i += gridDim.x * 256)
        atomicAdd(&h[ei[e + i] >> BSH], 1);
    __syncthreads();
    if (t < nbuc && h[t]) atomicAdd(&bucket_cnt[t], h[t]);
}

// ---------------- W prep (blocks 0..127) + bucket scan (block 128) ---------

__global__ __launch_bounds__(256) void prep_scan_kernel(const float* __restrict__ W1,
                                                        const float* __restrict__ W2,
                                                        ushort* __restrict__ wt,
                                                        const int* __restrict__ bucket_cnt,
                                                        int* __restrict__ bucket_base,
                                                        int* __restrict__ gcur, int nbuc) {
    if (blockIdx.x == 128) {
        __shared__ int aux[256];
        int t = threadIdx.x;
        int v = (t < nbuc) ? bucket_cnt[t] : 0;
        int incl = scan256_incl(aux, t, v);
        int base = incl - v;
        bucket_base[t] = base;
        gcur[t] = base;
        if (t == nbuc - 1) bucket_base[nbuc] = incl;
        return;
    }
    int idx = blockIdx.x * 256 + threadIdx.x;     // 2*128*128 elements
    int m = idx >> 14;
    int c = (idx >> 7) & 127;
    int r = idx & 127;
    const float* W = m ? W2 : W1;
    float w = W[r * F + c];
    ushort hi = f2bf(w);
    float whi = __uint_as_float((uint)hi << 16);
    ushort lo = f2bf(w - whi);
    wt[((m * 2 + 0) * F + c) * F + r] = hi;
    wt[((m * 2 + 1) * F + c) * F + r] = lo;
}

// ---------------- pass B: bucketed edge dump (LDS multisplit) --------------

__global__ __launch_bounds__(256) void passB_kernel(const int* __restrict__ ei,
                                                    int* __restrict__ gcur,
                                                    uint2* __restrict__ ebuf, int e) {
    __shared__ uint2 stage[EB];
    __shared__ int h[256], start[256], cur[256], claim[256], aux[256];
    int t = threadIdx.x;
    h[t] = 0;
    __syncthreads();
    int base = blockIdx.x * EB;
    int s_r[16], d_r[16];
#pragma unroll
    for (int k = 0; k < 16; ++k) {
        int i = base + k * 256 + t;
        int sv = -1, dv = 0;
        if (i < e) {
            sv = ei[i];
            dv = ei[e + i];
            atomicAdd(&h[dv >> BSH], 1);
        }
        s_r[k] = sv; d_r[k] = dv;
    }
    __syncthreads();
    int hv = h[t];
    int incl = scan256_incl(aux, t, hv);
    start[t] = incl - hv;
    cur[t]   = incl - hv;
    claim[t] = (hv > 0) ? atomicAdd(&gcur[t], hv) : 0;
    __syncthreads();
#pragma unroll
    for (int k = 0; k < 16; ++k) {
        if (s_r[k] >= 0) {
            int b = d_r[k] >> BSH;
            int r = atomicAdd(&cur[b], 1);
            stage[r] = make_uint2((uint)s_r[k], (uint)d_r[k]);
        }
    }
    __syncthreads();
    int valid = min(EB, e - base);
#pragma unroll
    for (int k = 0; k < 16; ++k) {
        int idx = k * 256 + t;
        if (idx < valid) {
            uint2 ed = stage[idx];
            int b = (int)(ed.y >> BSH);
            ebuf[claim[b] + (idx - start[b])] = ed;
        }
    }
}

// ---------------- pass C1: per-bucket fine hist -> rp, dis -----------------

__global__ __launch_bounds__(256) void passC1_kernel(const uint2* __restrict__ ebuf,
                                                     const int* __restrict__ bucket_base,
                                                     int* __restrict__ rp,
                                                     float* __restrict__ dis, int n) {
    __shared__ int h[512];
    __shared__ int aux[256];
    int t = threadIdx.x, b = blockIdx.x;
    int v0 = b << BSH;
    h[t] = 0; h[t + 256] = 0;
    __syncthreads();
    int ebeg = bucket_base[b], eend = bucket_base[b + 1];
    for (int i = ebeg + t; i < eend; i += 256)
        atomicAdd(&h[(int)ebuf[i].y - v0], 1);
    __syncthreads();
#pragma unroll
    for (int k = 0; k < 2; ++k) {
        int v = v0 + t + k * 256;
        if (v < n) dis[v] = rsqrtf((float)(h[t + k * 256] + 1));
    }
    int p = h[2 * t] + h[2 * t + 1];
    int incl = scan256_incl(aux, t, p);
    int ex = incl - p;
    int v = v0 + 2 * t;
    if (v <= n)     rp[v]     = ebeg + ex;
    if (v + 1 <= n) rp[v + 1] = ebeg + ex + h[2 * t];
}

// ---------------- pass C2: per-bucket scatter -> ew=(src, norm) ------------

__global__ __launch_bounds__(256) void passC2_kernel(const uint2* __restrict__ ebuf,
                                                     const int* __restrict__ bucket_base,
                                                     const int* __restrict__ rp,
                                                     const float* __restrict__ dis,
                                                     uint2* __restrict__ ew, int n) {
    __shared__ int cur[512];
    __shared__ float dl[512];
    int t = threadIdx.x, b = blockIdx.x;
    int v0 = b << BSH;
#pragma unroll
    for (int k = 0; k < 2; ++k) {
        int idx = t + k * 256, v = v0 + idx;
        cur[idx] = (v < n) ? rp[v] : 0;
        dl[idx]  = (v < n) ? dis[v] : 0.f;
    }
    __syncthreads();
    int ebeg = bucket_base[b], eend = bucket_base[b + 1];
    for (int i = ebeg + t; i < eend; i += 256) {
        uint2 ed = ebuf[i];
        int s = (int)ed.x, d = (int)ed.y - v0;
        float w = dis[s] * dl[d];
        int p = atomicAdd(&cur[d], 1);
        ew[p] = make_uint2(ed.x, __float_as_uint(w));
    }
}

// ---------------- GEMM: persistent, B-in-registers -------------------------
// grid ~512 blocks (2/CU) x 256 thr = 4 waves; wave w owns cols [w*32,+32).
// Per strip (128 rows): A staged bf16 swizzled LDS (double-buffered),
// 128 MFMA/wave, C via LDS-reuse epilogue. B (hi+lo) loaded once to VGPRs.

template <bool F32IN>
__global__ __launch_bounds__(256) void gemm_mfma_kernel(const float* __restrict__ Af,
                                                        const uint* __restrict__ Ab,
                                                        const ushort* __restrict__ wt,
                                                        ushort* __restrict__ C,
                                                        int n, int nstrips) {
    __shared__ uint4 As4[2][2048];       // 2 x 32 KB
    const int t = threadIdx.x;
    const int w = t >> 6;
    const int lane = t & 63;
    const int kg = lane >> 4;            // k-group 0..3
    const int lr = lane & 15;

    // ---- B fragments, whole kernel ----
    const uint4* Bg = (const uint4*)wt;  // [part][col][kgran] 16B granules
    s16x8 bfr[2][2][4];                  // [part][ctile][ks]
#pragma unroll
    for (int part = 0; part < 2; ++part)
#pragma unroll
        for (int c = 0; c < 2; ++c)
#pragma unroll
            for (int ks = 0; ks < 4; ++ks) {
                int col = w * 32 + c * 16 + lr;
                uint4 bu = Bg[part * F * 16 + col * 16 + ks * 4 + kg];
                bfr[part][c][ks] = *(const s16x8*)&bu;
            }

    auto load_strip = [&](int strip, uint4* st) {
        int r0 = strip * 128;
#pragma unroll
        for (int p = 0; p < 8; ++p) {
            int g = p * 256 + t;
            int row = g >> 4, q = g & 15;
            int c8 = q ^ (row & 7);          // pre-swizzled source granule
            uint4 v = make_uint4(0u, 0u, 0u, 0u);
            int gr = r0 + row;
            if (gr < n) {
                if (F32IN) {
                    const float* a = Af + (size_t)gr * F + c8 * 8;
                    float4 f0 = *(const float4*)a;
                    float4 f1 = *(const float4*)(a + 4);
                    v.x = pack_bf2(f0.x, f0.y);
                    v.y = pack_bf2(f0.z, f0.w);
                    v.z = pack_bf2(f1.x, f1.y);
                    v.w = pack_bf2(f1.z, f1.w);
                } else {
                    v = *(const uint4*)(Ab + (size_t)gr * 64 + c8 * 4);
                }
            }
            st[p] = v;
        }
    };

    int s = blockIdx.x;
    if (s >= nstrips) return;
    uint4 st[8];
    load_strip(s, st);
    int buf = 0;
    for (; s < nstrips; s += gridDim.x) {
#pragma unroll
        for (int p = 0; p < 8; ++p) As4[buf][p * 256 + t] = st[p];
        __syncthreads();
        int s2 = s + gridDim.x;
        if (s2 < nstrips) load_strip(s2, st);   // overlaps with compute

        f32x4 acc[8][2];
#pragma unroll
        for (int r = 0; r < 8; ++r)
#pragma unroll
            for (int c = 0; c < 2; ++c) acc[r][c] = (f32x4){0.f, 0.f, 0.f, 0.f};

        const s16x8* As8 = (const s16x8*)As4[buf];
#pragma unroll
        for (int ks = 0; ks < 4; ++ks) {
            s16x8 afr[8];
#pragma unroll
            for (int r = 0; r < 8; ++r) {
                int row = r * 16 + lr;
                afr[r] = As8[row * 16 + ((ks * 4 + kg) ^ (row & 7))];
            }
#pragma unroll
            for (int r = 0; r < 8; ++r)
#pragma unroll
                for (int c = 0; c < 2; ++c) {
                    acc[r][c] = __builtin_amdgcn_mfma_f32_16x16x32_bf16(afr[r], bfr[0][c][ks], acc[r][c], 0, 0, 0);
                    acc[r][c] = __builtin_amdgcn_mfma_f32_16x16x32_bf16(afr[r], bfr[1][c][ks], acc[r][c], 0, 0, 0);
                }
        }
        __syncthreads();

        // epilogue: bf16 C into the just-consumed buffer, then coalesced out
        ushort* Cs = (ushort*)As4[buf];
#pragma unroll
        for (int r = 0; r < 8; ++r)
#pragma unroll
            for (int c = 0; c < 2; ++c)
#pragma unroll
                for (int reg = 0; reg < 4; ++reg) {
                    int row = r * 16 + kg * 4 + reg;
                    int col = w * 32 + c * 16 + lr;
                    Cs[row * F + col] = f2bf(acc[r][c][reg]);
                }
        __syncthreads();
        int r0 = s * 128;
#pragma unroll
        for (int p = 0; p < 8; ++p) {
            int g = p * 256 + t;
            int row = g >> 4, c8 = g & 15;
            if (r0 + row < n)
                *(uint4*)(C + (size_t)(r0 + row) * F + c8 * 8) = As4[buf][g];
        }
        buf ^= 1;
    }
}

// ---------------- pull aggregation + bias + relu (bf16 in/out) -------------
// one independent wave per node; lane owns cols {2*lane, 2*lane+1};
// 16 outstanding gathers (latency-bound regime).

__global__ __launch_bounds__(256) void agg_kernel(const uint* __restrict__ h2,
                                                  const int* __restrict__ rp,
                                                  const uint2* __restrict__ ew,
                                                  const float* __restrict__ dis,
                                                  const float* __restrict__ bias,
                                                  uint* __restrict__ out2, int n) {
    int wid = __builtin_amdgcn_readfirstlane(threadIdx.x >> 6);
    int node = blockIdx.x * 4 + wid;
    if (node >= n) return;
    int lane = threadIdx.x & 63;
    float di = dis[node];
    int beg = rp[node], end = rp[node + 1];
    uint hv = h2[((uint)node << 6) | lane];
    float w0 = di * di;
    float ax = w0 * bf_lo(hv);
    float ay = w0 * bf_hi(hv);
    int j = beg;
    for (; j + 16 <= end; j += 16) {
        uint2 E[16];
        uint v[16];
#pragma unroll
        for (int k = 0; k < 16; ++k) E[k] = ew[j + k];
#pragma unroll
        for (int k = 0; k < 16; ++k) v[k] = h2[(E[k].x << 6) | lane];
#pragma unroll
        for (int k = 0; k < 16; ++k) {
            float we = __uint_as_float(E[k].y);
            ax = fmaf(we, bf_lo(v[k]), ax);
            ay = fmaf(we, bf_hi(v[k]), ay);
        }
    }
    for (; j + 4 <= end; j += 4) {
        uint2 E0 = ew[j], E1 = ew[j + 1], E2 = ew[j + 2], E3 = ew[j + 3];
        uint v0 = h2[(E0.x << 6) | lane];
        uint v1 = h2[(E1.x << 6) | lane];
        uint v2 = h2[(E2.x << 6) | lane];
        uint v3 = h2[(E3.x << 6) | lane];
        float w0e = __uint_as_float(E0.y), w1e = __uint_as_float(E1.y);
        float w2e = __uint_as_float(E2.y), w3e = __uint_as_float(E3.y);
        ax = fmaf(w0e, bf_lo(v0), ax); ay = fmaf(w0e, bf_hi(v0), ay);
        ax = fmaf(w1e, bf_lo(v1), ax); ay = fmaf(w1e, bf_hi(v1), ay);
        ax = fmaf(w2e, bf_lo(v2), ax); ay = fmaf(w2e, bf_hi(v2), ay);
        ax = fmaf(w3e, bf_lo(v3), ax); ay = fmaf(w3e, bf_hi(v3), ay);
    }
    for (; j < end; ++j) {
        uint2 E0 = ew[j];
        uint v0 = h2[(E0.x << 6) | lane];
        float w0e = __uint_as_float(E0.y);
        ax = fmaf(w0e, bf_lo(v0), ax);
        ay = fmaf(w0e, bf_hi(v0), ay);
    }
    float2 b = ((const float2*)bias)[lane];
    ax = fmaxf(ax + b.x, 0.f);
    ay = fmaxf(ay + b.y, 0.f);
    out2[((uint)node << 6) | lane] = pack_bf2(ax, ay);
}

// ---------------- global mean pool (batch sorted, bf16 in, f32 out) --------

__global__ __launch_bounds__(256) void pool_kernel(const uint* __restrict__ h2,
                                                   const int* __restrict__ batch,
                                                   float* __restrict__ out, int n) {
    __shared__ int sb[2];
    __shared__ float red[4][F];
    int g = blockIdx.x;
    int t = threadIdx.x;
    if (t < 2) {
        int target = g + t;
        int lo = 0, hi = n;
        while (lo < hi) {
            int mid = (lo + hi) >> 1;
            if (batch[mid] < target) lo = mid + 1; else hi = mid;
        }
        sb[t] = lo;
    }
    __syncthreads();
    int start = sb[0], end = sb[1];
    int lane = t & 63, w = t >> 6;
    float sx = 0.f, sy = 0.f;
    for (int i = start + w; i < end; i += 4) {
        uint v = h2[((uint)i << 6) | lane];
        sx += bf_lo(v);
        sy += bf_hi(v);
    }
    red[w][lane * 2] = sx;
    red[w][lane * 2 + 1] = sy;
    __syncthreads();
    if (w == 0) {
        float s0 = red[0][lane * 2] + red[1][lane * 2] + red[2][lane * 2] + red[3][lane * 2];
        float s1 = red[0][lane * 2 + 1] + red[1][lane * 2 + 1] + red[2][lane * 2 + 1] + red[3][lane * 2 + 1];
        float inv = 1.f / fmaxf((float)(end - start), 1.f);
        out[(size_t)g * F + lane * 2]     = s0 * inv;
        out[(size_t)g * F + lane * 2 + 1] = s1 * inv;
    }
}

// ---------------------------------------------------------------------------

extern "C" void kernel_launch(void* const* d_in, const int* in_sizes, int n_in,
                              void* d_out, int out_size, void* d_ws, size_t ws_size,
                              hipStream_t stream) {
    const float* x     = (const float*)d_in[0];
    const int*   ei    = (const int*)d_in[1];
    const int*   batch = (const int*)d_in[2];
    const float* W1    = (const float*)d_in[3];
    const float* b1    = (const float*)d_in[4];
    const float* W2    = (const float*)d_in[5];
    const float* b2    = (const float*)d_in[6];
    float* out = (float*)d_out;

    const int n = in_sizes[0] / F;       // 100000
    const int e = in_sizes[1] / 2;       // 1600000
    const int g = out_size / F;          // 512
    const int nbuc = (n + (1 << BSH) - 1) >> BSH;   // 196

    char* ws = (char*)d_ws;
    size_t off = 0;
    auto alloc = [&](size_t bytes) -> char* {
        char* p = ws + off;
        off += (bytes + 255) & ~(size_t)255;
        return p;
    };
    float*  dis   = (float*)alloc((size_t)n * 4);
    int*    rp    = (int*)  alloc((size_t)(n + 1) * 4);
    int*    bcnt  = (int*)  alloc(256 * 4);
    int*    bbase = (int*)  alloc(257 * 4);
    int*    gcur  = (int*)  alloc(256 * 4);
    uint2*  ebuf  = (uint2*)alloc((size_t)e * 8);
    uint2*  ew    = (uint2*)alloc((size_t)e * 8);
    ushort* wt    = (ushort*)alloc((size_t)4 * F * F * 2);
    uint*   hbuf  = (uint*) alloc((size_t)n * F * 2);
    uint*   abuf  = (uint*) alloc((size_t)n * F * 2);
    (void)ws_size;

    // --- CSR build (bucketed) + W prep ---
    hipMemsetAsync(bcnt, 0, 256 * 4, stream);
    passA_kernel<<<256, 256, 0, stream>>>(ei, bcnt, e, nbuc);
    prep_scan_kernel<<<129, 256, 0, stream>>>(W1, W2, wt, bcnt, bbase, gcur, nbuc);
    passB_kernel<<<(e + EB - 1) / EB, 256, 0, stream>>>(ei, gcur, ebuf, e);
    passC1_kernel<<<nbuc, 256, 0, stream>>>(ebuf, bbase, rp, dis, n);
    passC2_kernel<<<nbuc, 256, 0, stream>>>(ebuf, bbase, rp, dis, ew, n);

    const int nstrips = (n + 127) / 128;
    int ggrid = nstrips < 512 ? nstrips : 512;
    // --- layer 1 ---
    gemm_mfma_kernel<true><<<ggrid, 256, 0, stream>>>(x, nullptr, wt, (ushort*)hbuf, n, nstrips);
    agg_kernel<<<(n + 3) / 4, 256, 0, stream>>>(hbuf, rp, ew, dis, b1, abuf, n);
    // --- layer 2 ---
    gemm_mfma_kernel<false><<<ggrid, 256, 0, stream>>>(nullptr, abuf, wt + 2 * F * F, (ushort*)hbuf, n, nstrips);
    agg_kernel<<<(n + 3) / 4, 256, 0, stream>>>(hbuf, rp, ew, dis, b2, abuf, n);
    // --- pool ---
    pool_kernel<<<g, 256, 0, stream>>>(abuf, batch, out, n);
}

// Round 8
// 338.087 us; speedup vs baseline: 1.3082x; 1.0348x over previous
//
#include <hip/hip_runtime.h>
#include <stddef.h>

// ---------------------------------------------------------------------------
// 2-layer GCN, bf16 intermediates + MFMA GEMMs + bucketed CSR build.
// h = relu(Agg(x@W1)+b1); h = relu(Agg(h@W2)+b2); out = mean pool per graph.
// CSR: 391 buckets of 256 nodes (BSH=8), packed ebuf (dloc<<24|src).
// GEMM: one 128-row strip per block, single 32KB LDS buffer, B(hi+lo) in regs.
// Agg: 1 wave per node, 16 outstanding gathers (measured ~92% of random-BW).
// ---------------------------------------------------------------------------

#define F 128
#define EB 4096          // edges per passB block
#define BSH 8            // bucket = dst >> 8 (256 nodes per bucket)

typedef unsigned int uint;
typedef unsigned short ushort;
typedef __attribute__((ext_vector_type(8))) short s16x8;   // 8 bf16
typedef __attribute__((ext_vector_type(4))) float f32x4;

__device__ __forceinline__ float bf_lo(uint v) { return __uint_as_float(v << 16); }
__device__ __forceinline__ float bf_hi(uint v) { return __uint_as_float(v & 0xffff0000u); }
__device__ __forceinline__ ushort f2bf(float f) {
    uint u = __float_as_uint(f);
    u += 0x7fffu + ((u >> 16) & 1u);   // RNE
    return (ushort)(u >> 16);
}
__device__ __forceinline__ uint pack_bf2(float lo, float hi) {
    return (uint)f2bf(lo) | ((uint)f2bf(hi) << 16);
}

// inclusive Hillis-Steele scan over 256 entries (all 256 threads must call)
__device__ __forceinline__ int scan256_incl(int* s, int t, int v) {
    s[t] = v;
    __syncthreads();
#pragma unroll
    for (int d = 1; d < 256; d <<= 1) {
        int y = (t >= d) ? s[t - d] : 0;
        __syncthreads();
        s[t] += y;
        __syncthreads();
    }
    return s[t];
}

// ---------------- pass A: coarse bucket histogram (512 buckets max) --------

__global__ __launch_bounds__(256) void passA_kernel(const int* __restrict__ ei,
                                                    int* __restrict__ bucket_cnt,
                                                    int e, int nbuc) {
    __shared__ int h[512];
    int t = threadIdx.x;
    h[t] = 0; h[t + 256] = 0;
    __syncthreads();
    for (int i = blockIdx.x * 256 + t; i < e; i += gridDim.x * 256)
        atomicAdd(&h[ei[e + i] >> BSH], 1);
    __syncthreads();
#pragma unroll
    for (int k = 0; k < 2; ++k) {
        int b = t + k * 256;
        if (b < nbuc && h[b]) atomicAdd(&bucket_cnt[b], h[b]);
    }
}

// ---------------- W prep (blocks 0..127) + bucket scan512 (block 128) ------

__global__ __launch_bounds__(256) void prep_scan_kernel(const float* __restrict__ W1,
                                                        const float* __restrict__ W2,
                                                        ushort* __restrict__ wt,
                                                        const int* __restrict__ bucket_cnt,
                                                        int* __restrict__ bucket_base,
                                                        int* __restrict__ gcur, int nbuc) {
    if (blockIdx.x == 128) {
        __shared__ int aux[256];
        int t = threadIdx.x;
        int c0 = (2 * t < nbuc) ? bucket_cnt[2 * t] : 0;
        int c1 = (2 * t + 1 < nbuc) ? bucket_cnt[2 * t + 1] : 0;
        int p = c0 + c1;
        int incl = scan256_incl(aux, t, p);
        int ex = incl - p;
        bucket_base[2 * t] = ex;
        bucket_base[2 * t + 1] = ex + c0;
        gcur[2 * t] = ex;
        gcur[2 * t + 1] = ex + c0;
        if (t == 255) bucket_base[512] = incl;
        return;
    }
    int idx = blockIdx.x * 256 + threadIdx.x;     // 2*128*128 elements
    int m = idx >> 14;
    int c = (idx >> 7) & 127;
    int r = idx & 127;
    const float* W = m ? W2 : W1;
    float w = W[r * F + c];
    ushort hi = f2bf(w);
    float whi = __uint_as_float((uint)hi << 16);
    ushort lo = f2bf(w - whi);
    wt[((m * 2 + 0) * F + c) * F + r] = hi;
    wt[((m * 2 + 1) * F + c) * F + r] = lo;
}

// ---------------- pass B: bucketed edge dump (LDS multisplit, 512 buckets) -
// ebuf entry packed: (dloc << 24) | src   (src < 2^17, dloc < 2^8)

__global__ __launch_bounds__(256) void passB_kernel(const int* __restrict__ ei,
                                                    int* __restrict__ gcur,
                                                    uint* __restrict__ ebuf, int e) {
    __shared__ uint2 stage[EB];                       // 32 KB
    __shared__ int h[512], start[512], cur[512], claim[512], aux[256];
    int t = threadIdx.x;
    h[t] = 0; h[t + 256] = 0;
    __syncthreads();
    int base = blockIdx.x * EB;
    int s_r[16], d_r[16];
#pragma unroll
    for (int k = 0; k < 16; ++k) {
        int i = base + k * 256 + t;
        int sv = -1, dv = 0;
        if (i < e) {
            sv = ei[i];
            dv = ei[e + i];
            atomicAdd(&h[dv >> BSH], 1);
        }
        s_r[k] = sv; d_r[k] = dv;
    }
    __syncthreads();
    {
        int h0 = h[2 * t], h1 = h[2 * t + 1];
        int p = h0 + h1;
        int incl = scan256_incl(aux, t, p);
        int ex = incl - p;
        start[2 * t] = ex;          start[2 * t + 1] = ex + h0;
        cur[2 * t] = ex;            cur[2 * t + 1] = ex + h0;
        claim[2 * t]     = (h0 > 0) ? atomicAdd(&gcur[2 * t], h0) : 0;
        claim[2 * t + 1] = (h1 > 0) ? atomicAdd(&gcur[2 * t + 1], h1) : 0;
    }
    __syncthreads();
#pragma unroll
    for (int k = 0; k < 16; ++k) {
        if (s_r[k] >= 0) {
            int b = d_r[k] >> BSH;
            int r = atomicAdd(&cur[b], 1);
            stage[r] = make_uint2((uint)s_r[k], (uint)d_r[k]);
        }
    }
    __syncthreads();
    int valid = min(EB, e - base);
#pragma unroll
    for (int k = 0; k < 16; ++k) {
        int idx = k * 256 + t;
        if (idx < valid) {
            uint2 ed = stage[idx];
            int b = (int)(ed.y >> BSH);
            uint dloc = ed.y & ((1u << BSH) - 1u);
            ebuf[claim[b] + (idx - start[b])] = (dloc << 24) | ed.x;
        }
    }
}

// ---------------- pass C1: per-bucket fine hist -> rp, dis -----------------

__global__ __launch_bounds__(256) void passC1_kernel(const uint* __restrict__ ebuf,
                                                     const int* __restrict__ bucket_base,
                                                     int* __restrict__ rp,
                                                     float* __restrict__ dis, int n) {
    __shared__ int h[256];
    __shared__ int aux[256];
    int t = threadIdx.x, b = blockIdx.x;
    int v0 = b << BSH;
    h[t] = 0;
    __syncthreads();
    int ebeg = bucket_base[b], eend = bucket_base[b + 1];
    for (int i = ebeg + t; i < eend; i += 256)
        atomicAdd(&h[ebuf[i] >> 24], 1);
    __syncthreads();
    int cnt = h[t];
    int v = v0 + t;
    if (v < n) dis[v] = rsqrtf((float)(cnt + 1));
    int incl = scan256_incl(aux, t, cnt);
    int ex = incl - cnt;
    if (v < n) rp[v] = ebeg + ex;
    if (v == n - 1) rp[n] = ebeg + incl;
}

// ---------------- pass C2: per-bucket scatter -> ew=(src, norm) ------------

__global__ __launch_bounds__(256) void passC2_kernel(const uint* __restrict__ ebuf,
                                                     const int* __restrict__ bucket_base,
                                                     const int* __restrict__ rp,
                                                     const float* __restrict__ dis,
                                                     uint2* __restrict__ ew, int n) {
    __shared__ int cur[256];
    __shared__ float dl[256];
    int t = threadIdx.x, b = blockIdx.x;
    int v0 = b << BSH;
    int v = v0 + t;
    cur[t] = (v < n) ? rp[v] : 0;
    dl[t]  = (v < n) ? dis[v] : 0.f;
    __syncthreads();
    int ebeg = bucket_base[b], eend = bucket_base[b + 1];
    for (int i = ebeg + t; i < eend; i += 256) {
        uint ed = ebuf[i];
        uint src = ed & 0xFFFFFFu;
        int d = (int)(ed >> 24);
        float w = dis[src] * dl[d];
        int p = atomicAdd(&cur[d], 1);
        ew[p] = make_uint2(src, __float_as_uint(w));
    }
}

// ---------------- GEMM: one 128-row strip per block ------------------------
// 256 thr = 4 waves; wave w owns cols [w*32,+32). B(hi+lo) in regs (once),
// A staged bf16 swizzled in single 32KB LDS buffer, LDS-reuse C epilogue.

template <bool F32IN>
__global__ __launch_bounds__(256) void gemm_mfma_kernel(const float* __restrict__ Af,
                                                        const uint* __restrict__ Ab,
                                                        const ushort* __restrict__ wt,
                                                        ushort* __restrict__ C, int n) {
    __shared__ uint4 As4[2048];          // 32 KB
    const int t = threadIdx.x;
    const int w = t >> 6;
    const int lane = t & 63;
    const int kg = lane >> 4;            // k-group 0..3
    const int lr = lane & 15;
    const int r0 = blockIdx.x * 128;

    // ---- B fragments ----
    const uint4* Bg = (const uint4*)wt;  // [part][col][kgran] 16B granules
    s16x8 bfr[2][2][4];                  // [part][ctile][ks]
#pragma unroll
    for (int part = 0; part < 2; ++part)
#pragma unroll
        for (int c = 0; c < 2; ++c)
#pragma unroll
            for (int ks = 0; ks < 4; ++ks) {
                int col = w * 32 + c * 16 + lr;
                uint4 bu = Bg[part * F * 16 + col * 16 + ks * 4 + kg];
                bfr[part][c][ks] = *(const s16x8*)&bu;
            }

    // ---- stage A strip into swizzled LDS ----
#pragma unroll
    for (int p = 0; p < 8; ++p) {
        int g = p * 256 + t;
        int row = g >> 4, c8 = g & 15;
        uint4 v = make_uint4(0u, 0u, 0u, 0u);
        int gr = r0 + row;
        if (gr < n) {
            if (F32IN) {
                const float* a = Af + (size_t)gr * F + c8 * 8;
                float4 f0 = *(const float4*)a;
                float4 f1 = *(const float4*)(a + 4);
                v.x = pack_bf2(f0.x, f0.y);
                v.y = pack_bf2(f0.z, f0.w);
                v.z = pack_bf2(f1.x, f1.y);
                v.w = pack_bf2(f1.z, f1.w);
            } else {
                v = *(const uint4*)(Ab + (size_t)gr * 64 + c8 * 4);
            }
        }
        As4[row * 16 + (c8 ^ (row & 7))] = v;
    }
    __syncthreads();

    f32x4 acc[8][2];
#pragma unroll
    for (int r = 0; r < 8; ++r)
#pragma unroll
        for (int c = 0; c < 2; ++c) acc[r][c] = (f32x4){0.f, 0.f, 0.f, 0.f};

    const s16x8* As8 = (const s16x8*)As4;
#pragma unroll
    for (int ks = 0; ks < 4; ++ks) {
        s16x8 afr[8];
#pragma unroll
        for (int r = 0; r < 8; ++r) {
            int row = r * 16 + lr;
            afr[r] = As8[row * 16 + ((ks * 4 + kg) ^ (row & 7))];
        }
#pragma unroll
        for (int r = 0; r < 8; ++r)
#pragma unroll
            for (int c = 0; c < 2; ++c) {
                acc[r][c] = __builtin_amdgcn_mfma_f32_16x16x32_bf16(afr[r], bfr[0][c][ks], acc[r][c], 0, 0, 0);
                acc[r][c] = __builtin_amdgcn_mfma_f32_16x16x32_bf16(afr[r], bfr[1][c][ks], acc[r][c], 0, 0, 0);
            }
    }
    __syncthreads();

    // ---- epilogue: bf16 C via LDS, coalesced out ----
    ushort* Cs = (ushort*)As4;
#pragma unroll
    for (int r = 0; r < 8; ++r)
#pragma unroll
        for (int c = 0; c < 2; ++c)
#pragma unroll
            for (int reg = 0; reg < 4; ++reg) {
                int row = r * 16 + kg * 4 + reg;
                int col = w * 32 + c * 16 + lr;
                Cs[row * F + col] = f2bf(acc[r][c][reg]);
            }
    __syncthreads();
#pragma unroll
    for (int p = 0; p < 8; ++p) {
        int g = p * 256 + t;
        int row = g >> 4, c8 = g & 15;
        if (r0 + row < n)
            *(uint4*)(C + (size_t)(r0 + row) * F + c8 * 8) = As4[g];
    }
}

// ---------------- pull aggregation + bias + relu (bf16 in/out) -------------
// one independent wave per node; lane owns cols {2*lane, 2*lane+1};
// 16 outstanding gathers.

__global__ __launch_bounds__(256) void agg_kernel(const uint* __restrict__ h2,
                                                  const int* __restrict__ rp,
                                                  const uint2* __restrict__ ew,
                                                  const float* __restrict__ dis,
                                                  const float* __restrict__ bias,
                                                  uint* __restrict__ out2, int n) {
    int wid = __builtin_amdgcn_readfirstlane(threadIdx.x >> 6);
    int node = blockIdx.x * 4 + wid;
    if (node >= n) return;
    int lane = threadIdx.x & 63;
    float di = dis[node];
    int beg = rp[node], end = rp[node + 1];
    uint hv = h2[((uint)node << 6) | lane];
    float w0 = di * di;
    float ax = w0 * bf_lo(hv);
    float ay = w0 * bf_hi(hv);
    int j = beg;
    for (; j + 16 <= end; j += 16) {
        uint2 E[16];
        uint v[16];
#pragma unroll
        for (int k = 0; k < 16; ++k) E[k] = ew[j + k];
#pragma unroll
        for (int k = 0; k < 16; ++k) v[k] = h2[(E[k].x << 6) | lane];
#pragma unroll
        for (int k = 0; k < 16; ++k) {
            float we = __uint_as_float(E[k].y);
            ax = fmaf(we, bf_lo(v[k]), ax);
            ay = fmaf(we, bf_hi(v[k]), ay);
        }
    }
    for (; j + 4 <= end; j += 4) {
        uint2 E0 = ew[j], E1 = ew[j + 1], E2 = ew[j + 2], E3 = ew[j + 3];
        uint v0 = h2[(E0.x << 6) | lane];
        uint v1 = h2[(E1.x << 6) | lane];
        uint v2 = h2[(E2.x << 6) | lane];
        uint v3 = h2[(E3.x << 6) | lane];
        float w0e = __uint_as_float(E0.y), w1e = __uint_as_float(E1.y);
        float w2e = __uint_as_float(E2.y), w3e = __uint_as_float(E3.y);
        ax = fmaf(w0e, bf_lo(v0), ax); ay = fmaf(w0e, bf_hi(v0), ay);
        ax = fmaf(w1e, bf_lo(v1), ax); ay = fmaf(w1e, bf_hi(v1), ay);
        ax = fmaf(w2e, bf_lo(v2), ax); ay = fmaf(w2e, bf_hi(v2), ay);
        ax = fmaf(w3e, bf_lo(v3), ax); ay = fmaf(w3e, bf_hi(v3), ay);
    }
    for (; j < end; ++j) {
        uint2 E0 = ew[j];
        uint v0 = h2[(E0.x << 6) | lane];
        float w0e = __uint_as_float(E0.y);
        ax = fmaf(w0e, bf_lo(v0), ax);
        ay = fmaf(w0e, bf_hi(v0), ay);
    }
    float2 b = ((const float2*)bias)[lane];
    ax = fmaxf(ax + b.x, 0.f);
    ay = fmaxf(ay + b.y, 0.f);
    out2[((uint)node << 6) | lane] = pack_bf2(ax, ay);
}

// ---------------- global mean pool (batch sorted, bf16 in, f32 out) --------

__global__ __launch_bounds__(256) void pool_kernel(const uint* __restrict__ h2,
                                                   const int* __restrict__ batch,
                                                   float* __restrict__ out, int n) {
    __shared__ int sb[2];
    __shared__ float red[4][F];
    int g = blockIdx.x;
    int t = threadIdx.x;
    if (t < 2) {
        int target = g + t;
        int lo = 0, hi = n;
        while (lo < hi) {
            int mid = (lo + hi) >> 1;
            if (batch[mid] < target) lo = mid + 1; else hi = mid;
        }
        sb[t] = lo;
    }
    __syncthreads();
    int start = sb[0], end = sb[1];
    int lane = t & 63, w = t >> 6;
    float sx = 0.f, sy = 0.f;
    for (int i = start + w; i < end; i += 4) {
        uint v = h2[((uint)i << 6) | lane];
        sx += bf_lo(v);
        sy += bf_hi(v);
    }
    red[w][lane * 2] = sx;
    red[w][lane * 2 + 1] = sy;
    __syncthreads();
    if (w == 0) {
        float s0 = red[0][lane * 2] + red[1][lane * 2] + red[2][lane * 2] + red[3][lane * 2];
        float s1 = red[0][lane * 2 + 1] + red[1][lane * 2 + 1] + red[2][lane * 2 + 1] + red[3][lane * 2 + 1];
        float inv = 1.f / fmaxf((float)(end - start), 1.f);
        out[(size_t)g * F + lane * 2]     = s0 * inv;
        out[(size_t)g * F + lane * 2 + 1] = s1 * inv;
    }
}

// ---------------------------------------------------------------------------

extern "C" void kernel_launch(void* const* d_in, const int* in_sizes, int n_in,
                              void* d_out, int out_size, void* d_ws, size_t ws_size,
                              hipStream_t stream) {
    const float* x     = (const float*)d_in[0];
    const int*   ei    = (const int*)d_in[1];
    const int*   batch = (const int*)d_in[2];
    const float* W1    = (const float*)d_in[3];
    const float* b1    = (const float*)d_in[4];
    const float* W2    = (const float*)d_in[5];
    const float* b2    = (const float*)d_in[6];
    float* out = (float*)d_out;

    const int n = in_sizes[0] / F;       // 100000
    const int e = in_sizes[1] / 2;       // 1600000
    const int g = out_size / F;          // 512
    const int nbuc = (n + (1 << BSH) - 1) >> BSH;   // 391

    char* ws = (char*)d_ws;
    size_t off = 0;
    auto alloc = [&](size_t bytes) -> char* {
        char* p = ws + off;
        off += (bytes + 255) & ~(size_t)255;
        return p;
    };
    float*  dis   = (float*)alloc((size_t)n * 4);
    int*    rp    = (int*)  alloc((size_t)(n + 1) * 4);
    int*    bcnt  = (int*)  alloc(512 * 4);
    int*    bbase = (int*)  alloc(513 * 4);
    int*    gcur  = (int*)  alloc(512 * 4);
    uint*   ebuf  = (uint*) alloc((size_t)e * 4);
    uint2*  ew    = (uint2*)alloc((size_t)e * 8);
    ushort* wt    = (ushort*)alloc((size_t)4 * F * F * 2);
    uint*   hbuf  = (uint*) alloc((size_t)n * F * 2);
    uint*   abuf  = (uint*) alloc((size_t)n * F * 2);
    (void)ws_size;

    // --- CSR build (bucketed) + W prep ---
    hipMemsetAsync(bcnt, 0, 512 * 4, stream);
    passA_kernel<<<256, 256, 0, stream>>>(ei, bcnt, e, nbuc);
    prep_scan_kernel<<<129, 256, 0, stream>>>(W1, W2, wt, bcnt, bbase, gcur, nbuc);
    passB_kernel<<<(e + EB - 1) / EB, 256, 0, stream>>>(ei, gcur, ebuf, e);
    passC1_kernel<<<nbuc, 256, 0, stream>>>(ebuf, bbase, rp, dis, n);
    passC2_kernel<<<nbuc, 256, 0, stream>>>(ebuf, bbase, rp, dis, ew, n);

    const int nstrips = (n + 127) / 128;   // 782
    // --- layer 1 ---
    gemm_mfma_kernel<true><<<nstrips, 256, 0, stream>>>(x, nullptr, wt, (ushort*)hbuf, n);
    agg_kernel<<<(n + 3) / 4, 256, 0, stream>>>(hbuf, rp, ew, dis, b1, abuf, n);
    // --- layer 2 ---
    gemm_mfma_kernel<false><<<nstrips, 256, 0, stream>>>(nullptr, abuf, wt + 2 * F * F, (ushort*)hbuf, n);
    agg_kernel<<<(n + 3) / 4, 256, 0, stream>>>(hbuf, rp, ew, dis, b2, abuf, n);
    // --- pool ---
    pool_kernel<<<g, 256, 0, stream>>>(abuf, batch, out, n);
}

// Round 9
// 328.065 us; speedup vs baseline: 1.3482x; 1.0305x over previous
//
#include <hip/hip_runtime.h>
#include <stddef.h>

// ---------------------------------------------------------------------------
// 2-layer GCN, bf16 intermediates + MFMA GEMMs + bucketed CSR build.
// h = relu(Agg(x@W1)+b1); h = relu(Agg(h@W2)+b2); out = mean pool per graph.
// CSR: fixed-capacity buckets (dst>>8, CAP=8192), passB multisplit claims via
// zero-init gcur atomics (no passA/scan); fused per-bucket hist+scan+scatter.
// Agg: 1 wave/node, 16 outstanding gathers, norm = dis[src]*dis[dst] on the
// fly (dis table is L2-resident). GEMM: MFMA, B(hi+lo) in regs.
// ---------------------------------------------------------------------------

#define F 128
#define EB 4096          // edges per passB block
#define BSH 8            // bucket = dst >> 8 (256 nodes per bucket)
#define CAP 8192         // edge capacity per bucket (mean 4096, +64 sigma)

typedef unsigned int uint;
typedef unsigned short ushort;
typedef __attribute__((ext_vector_type(8))) short s16x8;   // 8 bf16
typedef __attribute__((ext_vector_type(4))) float f32x4;

__device__ __forceinline__ float bf_lo(uint v) { return __uint_as_float(v << 16); }
__device__ __forceinline__ float bf_hi(uint v) { return __uint_as_float(v & 0xffff0000u); }
__device__ __forceinline__ ushort f2bf(float f) {
    uint u = __float_as_uint(f);
    u += 0x7fffu + ((u >> 16) & 1u);   // RNE
    return (ushort)(u >> 16);
}
__device__ __forceinline__ uint pack_bf2(float lo, float hi) {
    return (uint)f2bf(lo) | ((uint)f2bf(hi) << 16);
}

// inclusive Hillis-Steele scan over 256 entries (all 256 threads must call)
__device__ __forceinline__ int scan256_incl(int* s, int t, int v) {
    s[t] = v;
    __syncthreads();
#pragma unroll
    for (int d = 1; d < 256; d <<= 1) {
        int y = (t >= d) ? s[t - d] : 0;
        __syncthreads();
        s[t] += y;
        __syncthreads();
    }
    return s[t];
}

// ---------------- pass B + W prep (fused, independent halves) --------------
// blocks [0, NB): bucketed edge dump via LDS multisplit; claims space in the
// fixed-capacity bucket region through zero-initialized gcur atomics.
// blocks [NB, NB+128): W split into bf16 hi + residual lo, transposed.
// ebuf entry packed: (dloc << 24) | src   (src < 2^17, dloc < 2^8)

__global__ __launch_bounds__(256) void passB_wprep_kernel(const int* __restrict__ ei,
                                                          int* __restrict__ gcur,
                                                          uint* __restrict__ ebuf, int e,
                                                          const float* __restrict__ W1,
                                                          const float* __restrict__ W2,
                                                          ushort* __restrict__ wt, int nb) {
    __shared__ uint2 stage[EB];                       // 32 KB
    __shared__ int h[512], start[512], cur[512], claim[512], aux[256];
    int t = threadIdx.x;
    if (blockIdx.x >= (uint)nb) {
        // ---- W prep half ----
        int idx = (blockIdx.x - nb) * 256 + t;        // 2*128*128 elements
        int m = idx >> 14;
        int c = (idx >> 7) & 127;
        int r = idx & 127;
        const float* W = m ? W2 : W1;
        float w = W[r * F + c];
        ushort hi = f2bf(w);
        float whi = __uint_as_float((uint)hi << 16);
        ushort lo = f2bf(w - whi);
        wt[((m * 2 + 0) * F + c) * F + r] = hi;
        wt[((m * 2 + 1) * F + c) * F + r] = lo;
        return;
    }
    h[t] = 0; h[t + 256] = 0;
    __syncthreads();
    int base = blockIdx.x * EB;
    int s_r[16], d_r[16];
#pragma unroll
    for (int k = 0; k < 16; ++k) {
        int i = base + k * 256 + t;
        int sv = -1, dv = 0;
        if (i < e) {
            sv = ei[i];
            dv = ei[e + i];
            atomicAdd(&h[dv >> BSH], 1);
        }
        s_r[k] = sv; d_r[k] = dv;
    }
    __syncthreads();
    {
        int h0 = h[2 * t], h1 = h[2 * t + 1];
        int p = h0 + h1;
        int incl = scan256_incl(aux, t, p);
        int ex = incl - p;
        start[2 * t] = ex;          start[2 * t + 1] = ex + h0;
        cur[2 * t] = ex;            cur[2 * t + 1] = ex + h0;
        claim[2 * t]     = (h0 > 0) ? atomicAdd(&gcur[2 * t], h0) : 0;
        claim[2 * t + 1] = (h1 > 0) ? atomicAdd(&gcur[2 * t + 1], h1) : 0;
    }
    __syncthreads();
#pragma unroll
    for (int k = 0; k < 16; ++k) {
        if (s_r[k] >= 0) {
            int b = d_r[k] >> BSH;
            int r = atomicAdd(&cur[b], 1);
            stage[r] = make_uint2((uint)s_r[k], (uint)d_r[k]);
        }
    }
    __syncthreads();
    int valid = min(EB, e - base);
#pragma unroll
    for (int k = 0; k < 16; ++k) {
        int idx = k * 256 + t;
        if (idx < valid) {
            uint2 ed = stage[idx];
            int b = (int)(ed.y >> BSH);
            uint dloc = ed.y & ((1u << BSH) - 1u);
            ebuf[(size_t)b * CAP + claim[b] + (idx - start[b])] = (dloc << 24) | ed.x;
        }
    }
}

// ---------------- pass C: per-bucket hist + scan + dis + scatter (fused) ---

__global__ __launch_bounds__(256) void passC_kernel(const uint* __restrict__ ebuf,
                                                    const int* __restrict__ gcur,
                                                    int* __restrict__ rbeg,
                                                    int* __restrict__ rend,
                                                    float* __restrict__ dis,
                                                    uint* __restrict__ ews, int n) {
    __shared__ int h[256], aux[256], cur[256];
    int t = threadIdx.x, b = blockIdx.x;
    int v0 = b << BSH;
    int ebeg = b * CAP;
    int count = gcur[b];
    h[t] = 0;
    __syncthreads();
    for (int i = t; i < count; i += 256)
        atomicAdd(&h[ebuf[ebeg + i] >> 24], 1);
    __syncthreads();
    int cnt = h[t];
    int v = v0 + t;
    if (v < n) dis[v] = rsqrtf((float)(cnt + 1));
    int incl = scan256_incl(aux, t, cnt);
    int ex = incl - cnt;
    if (v < n) { rbeg[v] = ebeg + ex; rend[v] = ebeg + ex + cnt; }
    cur[t] = ebeg + ex;
    __syncthreads();
    for (int i = t; i < count; i += 256) {
        uint ed = ebuf[ebeg + i];
        int p = atomicAdd(&cur[ed >> 24], 1);
        ews[p] = ed & 0xFFFFFFu;
    }
}

// ---------------- GEMM: one 128-row strip per block ------------------------
// 256 thr = 4 waves; wave w owns cols [w*32,+32). B(hi+lo) in regs,
// A staged bf16 swizzled in single 32KB LDS buffer, LDS-reuse C epilogue.

template <bool F32IN>
__global__ __launch_bounds__(256) void gemm_mfma_kernel(const float* __restrict__ Af,
                                                        const uint* __restrict__ Ab,
                                                        const ushort* __restrict__ wt,
                                                        ushort* __restrict__ C, int n) {
    __shared__ uint4 As4[2048];          // 32 KB
    const int t = threadIdx.x;
    const int w = t >> 6;
    const int lane = t & 63;
    const int kg = lane >> 4;            // k-group 0..3
    const int lr = lane & 15;
    const int r0 = blockIdx.x * 128;

    // ---- B fragments ----
    const uint4* Bg = (const uint4*)wt;  // [part][col][kgran] 16B granules
    s16x8 bfr[2][2][4];                  // [part][ctile][ks]
#pragma unroll
    for (int part = 0; part < 2; ++part)
#pragma unroll
        for (int c = 0; c < 2; ++c)
#pragma unroll
            for (int ks = 0; ks < 4; ++ks) {
                int col = w * 32 + c * 16 + lr;
                uint4 bu = Bg[part * F * 16 + col * 16 + ks * 4 + kg];
                bfr[part][c][ks] = *(const s16x8*)&bu;
            }

    // ---- stage A strip into swizzled LDS ----
#pragma unroll
    for (int p = 0; p < 8; ++p) {
        int g = p * 256 + t;
        int row = g >> 4, c8 = g & 15;
        uint4 v = make_uint4(0u, 0u, 0u, 0u);
        int gr = r0 + row;
        if (gr < n) {
            if (F32IN) {
                const float* a = Af + (size_t)gr * F + c8 * 8;
                float4 f0 = *(const float4*)a;
                float4 f1 = *(const float4*)(a + 4);
                v.x = pack_bf2(f0.x, f0.y);
                v.y = pack_bf2(f0.z, f0.w);
                v.z = pack_bf2(f1.x, f1.y);
                v.w = pack_bf2(f1.z, f1.w);
            } else {
                v = *(const uint4*)(Ab + (size_t)gr * 64 + c8 * 4);
            }
        }
        As4[row * 16 + (c8 ^ (row & 7))] = v;
    }
    __syncthreads();

    f32x4 acc[8][2];
#pragma unroll
    for (int r = 0; r < 8; ++r)
#pragma unroll
        for (int c = 0; c < 2; ++c) acc[r][c] = (f32x4){0.f, 0.f, 0.f, 0.f};

    const s16x8* As8 = (const s16x8*)As4;
#pragma unroll
    for (int ks = 0; ks < 4; ++ks) {
        s16x8 afr[8];
#pragma unroll
        for (int r = 0; r < 8; ++r) {
            int row = r * 16 + lr;
            afr[r] = As8[row * 16 + ((ks * 4 + kg) ^ (row & 7))];
        }
#pragma unroll
        for (int r = 0; r < 8; ++r)
#pragma unroll
            for (int c = 0; c < 2; ++c) {
                acc[r][c] = __builtin_amdgcn_mfma_f32_16x16x32_bf16(afr[r], bfr[0][c][ks], acc[r][c], 0, 0, 0);
                acc[r][c] = __builtin_amdgcn_mfma_f32_16x16x32_bf16(afr[r], bfr[1][c][ks], acc[r][c], 0, 0, 0);
            }
    }
    __syncthreads();

    // ---- epilogue: bf16 C via LDS, coalesced out ----
    ushort* Cs = (ushort*)As4;
#pragma unroll
    for (int r = 0; r < 8; ++r)
#pragma unroll
        for (int c = 0; c < 2; ++c)
#pragma unroll
            for (int reg = 0; reg < 4; ++reg) {
                int row = r * 16 + kg * 4 + reg;
                int col = w * 32 + c * 16 + lr;
                Cs[row * F + col] = f2bf(acc[r][c][reg]);
            }
    __syncthreads();
#pragma unroll
    for (int p = 0; p < 8; ++p) {
        int g = p * 256 + t;
        int row = g >> 4, c8 = g & 15;
        if (r0 + row < n)
            *(uint4*)(C + (size_t)(r0 + row) * F + c8 * 8) = As4[g];
    }
}

// ---------------- pull aggregation + bias + relu (bf16 in/out) -------------
// one independent wave per node; lane owns cols {2*lane, 2*lane+1};
// 16 outstanding gathers; norm = dis[src]*dis[node] (dis is L2-resident).

__global__ __launch_bounds__(256) void agg_kernel(const uint* __restrict__ h2,
                                                  const int* __restrict__ rbeg,
                                                  const int* __restrict__ rend,
                                                  const uint* __restrict__ ews,
                                                  const float* __restrict__ dis,
                                                  const float* __restrict__ bias,
                                                  uint* __restrict__ out2, int n) {
    int wid = __builtin_amdgcn_readfirstlane(threadIdx.x >> 6);
    int node = blockIdx.x * 4 + wid;
    if (node >= n) return;
    int lane = threadIdx.x & 63;
    float di = dis[node];
    int beg = rbeg[node], end = rend[node];
    uint hv = h2[((uint)node << 6) | lane];
    float w0 = di * di;
    float ax = w0 * bf_lo(hv);
    float ay = w0 * bf_hi(hv);
    int j = beg;
    for (; j + 16 <= end; j += 16) {
        uint S[16];
        float dsv[16];
        uint v[16];
#pragma unroll
        for (int k = 0; k < 16; ++k) S[k] = ews[j + k];
#pragma unroll
        for (int k = 0; k < 16; ++k) dsv[k] = dis[S[k]];
#pragma unroll
        for (int k = 0; k < 16; ++k) v[k] = h2[(S[k] << 6) | lane];
#pragma unroll
        for (int k = 0; k < 16; ++k) {
            float we = dsv[k] * di;
            ax = fmaf(we, bf_lo(v[k]), ax);
            ay = fmaf(we, bf_hi(v[k]), ay);
        }
    }
    for (; j + 4 <= end; j += 4) {
        uint S0 = ews[j], S1 = ews[j + 1], S2 = ews[j + 2], S3 = ews[j + 3];
        float d0 = dis[S0], d1 = dis[S1], d2 = dis[S2], d3 = dis[S3];
        uint v0 = h2[(S0 << 6) | lane];
        uint v1 = h2[(S1 << 6) | lane];
        uint v2 = h2[(S2 << 6) | lane];
        uint v3 = h2[(S3 << 6) | lane];
        float w0e = d0 * di, w1e = d1 * di, w2e = d2 * di, w3e = d3 * di;
        ax = fmaf(w0e, bf_lo(v0), ax); ay = fmaf(w0e, bf_hi(v0), ay);
        ax = fmaf(w1e, bf_lo(v1), ax); ay = fmaf(w1e, bf_hi(v1), ay);
        ax = fmaf(w2e, bf_lo(v2), ax); ay = fmaf(w2e, bf_hi(v2), ay);
        ax = fmaf(w3e, bf_lo(v3), ax); ay = fmaf(w3e, bf_hi(v3), ay);
    }
    for (; j < end; ++j) {
        uint S0 = ews[j];
        float w0e = dis[S0] * di;
        uint v0 = h2[(S0 << 6) | lane];
        ax = fmaf(w0e, bf_lo(v0), ax);
        ay = fmaf(w0e, bf_hi(v0), ay);
    }
    float2 b = ((const float2*)bias)[lane];
    ax = fmaxf(ax + b.x, 0.f);
    ay = fmaxf(ay + b.y, 0.f);
    out2[((uint)node << 6) | lane] = pack_bf2(ax, ay);
}

// ---------------- global mean pool (batch sorted, bf16 in, f32 out) --------

__global__ __launch_bounds__(256) void pool_kernel(const uint* __restrict__ h2,
                                                   const int* __restrict__ batch,
                                                   float* __restrict__ out, int n) {
    __shared__ int sb[2];
    __shared__ float red[4][F];
    int g = blockIdx.x;
    int t = threadIdx.x;
    if (t < 2) {
        int target = g + t;
        int lo = 0, hi = n;
        while (lo < hi) {
            int mid = (lo + hi) >> 1;
            if (batch[mid] < target) lo = mid + 1; else hi = mid;
        }
        sb[t] = lo;
    }
    __syncthreads();
    int start = sb[0], end = sb[1];
    int lane = t & 63, w = t >> 6;
    float sx = 0.f, sy = 0.f;
    for (int i = start + w; i < end; i += 4) {
        uint v = h2[((uint)i << 6) | lane];
        sx += bf_lo(v);
        sy += bf_hi(v);
    }
    red[w][lane * 2] = sx;
    red[w][lane * 2 + 1] = sy;
    __syncthreads();
    if (w == 0) {
        float s0 = red[0][lane * 2] + red[1][lane * 2] + red[2][lane * 2] + red[3][lane * 2];
        float s1 = red[0][lane * 2 + 1] + red[1][lane * 2 + 1] + red[2][lane * 2 + 1] + red[3][lane * 2 + 1];
        float inv = 1.f / fmaxf((float)(end - start), 1.f);
        out[(size_t)g * F + lane * 2]     = s0 * inv;
        out[(size_t)g * F + lane * 2 + 1] = s1 * inv;
    }
}

// ---------------------------------------------------------------------------

extern "C" void kernel_launch(void* const* d_in, const int* in_sizes, int n_in,
                              void* d_out, int out_size, void* d_ws, size_t ws_size,
                              hipStream_t stream) {
    const float* x     = (const float*)d_in[0];
    const int*   ei    = (const int*)d_in[1];
    const int*   batch = (const int*)d_in[2];
    const float* W1    = (const float*)d_in[3];
    const float* b1    = (const float*)d_in[4];
    const float* W2    = (const float*)d_in[5];
    const float* b2    = (const float*)d_in[6];
    float* out = (float*)d_out;

    const int n = in_sizes[0] / F;       // 100000
    const int e = in_sizes[1] / 2;       // 1600000
    const int g = out_size / F;          // 512
    const int nbuc = (n + (1 << BSH) - 1) >> BSH;   // 391
    const int nbB  = (e + EB - 1) / EB;             // 391

    char* ws = (char*)d_ws;
    size_t off = 0;
    auto alloc = [&](size_t bytes) -> char* {
        char* p = ws + off;
        off += (bytes + 255) & ~(size_t)255;
        return p;
    };
    float*  dis   = (float*)alloc((size_t)n * 4);
    int*    rbeg  = (int*)  alloc((size_t)n * 4);
    int*    rend  = (int*)  alloc((size_t)n * 4);
    int*    gcur  = (int*)  alloc(512 * 4);
    uint*   ebuf  = (uint*) alloc((size_t)nbuc * CAP * 4);
    uint*   ews   = (uint*) alloc((size_t)nbuc * CAP * 4);
    ushort* wt    = (ushort*)alloc((size_t)4 * F * F * 2);
    uint*   hbuf  = (uint*) alloc((size_t)n * F * 2);
    uint*   abuf  = (uint*) alloc((size_t)n * F * 2);
    (void)ws_size;

    // --- CSR build (fused) ---
    hipMemsetAsync(gcur, 0, 512 * 4, stream);
    passB_wprep_kernel<<<nbB + 128, 256, 0, stream>>>(ei, gcur, ebuf, e, W1, W2, wt, nbB);
    passC_kernel<<<nbuc, 256, 0, stream>>>(ebuf, gcur, rbeg, rend, dis, ews, n);

    const int nstrips = (n + 127) / 128;   // 782
    // --- layer 1 ---
    gemm_mfma_kernel<true><<<nstrips, 256, 0, stream>>>(x, nullptr, wt, (ushort*)hbuf, n);
    agg_kernel<<<(n + 3) / 4, 256, 0, stream>>>(hbuf, rbeg, rend, ews, dis, b1, abuf, n);
    // --- layer 2 ---
    gemm_mfma_kernel<false><<<nstrips, 256, 0, stream>>>(nullptr, abuf, wt + 2 * F * F, (ushort*)hbuf, n);
    agg_kernel<<<(n + 3) / 4, 256, 0, stream>>>(hbuf, rbeg, rend, ews, dis, b2, abuf, n);
    // --- pool ---
    pool_kernel<<<g, 256, 0, stream>>>(abuf, batch, out, n);
}